// Round 1
// baseline (1125.702 us; speedup 1.0000x reference)
//
#include <hip/hip_runtime.h>

#define NT 4
#define NN 50000
#define NE 800000
#define FD 256
#define HD 128
#define CH 512
#define NBINS 4096
#define CAPC 256
#define RSLOPE 0.22916666666666666f

#define NCH 32          // edge chunks per timestep
#define CHE (NE / NCH)  // 25000 edges per chunk
#define HALFN 25000     // node half-range (LDS u16 histogram fits 64KB)
#define WPH 12500       // packed u32 words per half
#define WPC 25000       // packed u32 words per chunk (all nodes)

#define C_NORM0 0
#define C_NORM1 1

#define SCAN_BLOCKS 49  // 49*1024 >= 50000
#define BT0SZ (HD * 2 * FD)  // per-t B-buffer elems (layer 0)
#define BT1SZ (HD * 2 * HD)  // per-t B-buffer elems (layer 1)

// startup dispatcher block ranges
#define SU_NORM0 0
#define SU_NORM1 1
#define SU_CVT_A 2      // 64 blocks: mlpW1 -> mW1t
#define SU_CVT_B 66     // 32 blocks: gcnW0 -> bt0 slot0 W-half
#define SU_CVT_C 98     // 16 blocks: gcnW1 -> bt1 slot0 W-half
#define SU_CAT0 114     // 1536 blocks
#define SU_CAT1 1650    // 384 blocks
#define SU_SPL0 2034    // 256 blocks
#define SU_SPL1 2290    // 64 blocks
#define SU_CPQ0 2354    // 32 blocks
#define SU_CPQ1 2386    // 16 blocks
#define SU_ZBAR 2402    // 1 block
#define SU_TOTAL 2403

typedef __attribute__((ext_vector_type(8))) short bf16x8;
typedef __attribute__((ext_vector_type(4))) float f32x4;

__device__ __forceinline__ float wsumf(float v) {
  for (int m = 32; m > 0; m >>= 1) v += __shfl_xor(v, m, 64);
  return v;
}

__device__ __forceinline__ unsigned short f2bf(float x) {
  unsigned int u = __float_as_uint(x);
  u += 0x7fffu + ((u >> 16) & 1u);
  return (unsigned short)(u >> 16);
}
__device__ __forceinline__ float bf2f(unsigned short h) {
  return __uint_as_float(((unsigned int)h) << 16);
}
__device__ __forceinline__ int sbin(float s) {
  int b = (int)floorf((s + 16.f) * 128.f);
  return max(0, min(NBINS - 1, b));
}

// Device-scope grid barrier, monotonic counter + generation index.
// All gridDim.x blocks must call with the same gen sequence.
__device__ __forceinline__ void gbar(unsigned int* bar, int nblk, int gen) {
  __syncthreads();
  if (threadIdx.x == 0) {
    __threadfence();              // release: publish this block's global writes
    atomicAdd(bar, 1u);
    unsigned int tgt = (unsigned int)(nblk * (gen + 1));
    while (atomicAdd(bar, 0u) < tgt) __builtin_amdgcn_s_sleep(2);
    __threadfence();              // acquire: invalidate stale cached lines
  }
  __syncthreads();
}

// ---- startup device bodies ----
__device__ __forceinline__ void d_norm(const float* s, int d, float* ctlf, int slot,
                                       float* red) {
  float v = ((int)threadIdx.x < d) ? s[threadIdx.x] * s[threadIdx.x] : 0.f;
  red[threadIdx.x] = v;
  __syncthreads();
  for (int o = 128; o > 0; o >>= 1) {
    if ((int)threadIdx.x < o) red[threadIdx.x] += red[threadIdx.x + o];
    __syncthreads();
  }
  if (threadIdx.x == 0) ctlf[slot] = fmaxf(sqrtf(red[0]), 1e-6f);
}

// transpose-convert: dst[c][roff + r] = cvt(src[r][c])
__device__ __forceinline__ void d_cvtT(int bx, int by, const float* __restrict__ src, int C,
                                       unsigned short* __restrict__ dhi,
                                       unsigned short* __restrict__ dlo,
                                       int ldd, int roff, float (*t)[33]) {
  int bc = bx * 32, br = by * 32;
  int lr = threadIdx.x >> 5, lc = threadIdx.x & 31;
#pragma unroll
  for (int q = 0; q < 4; ++q) {
    int r = br + lr + q * 8;
    t[lr + q * 8][lc] = src[(size_t)r * C + bc + lc];
  }
  __syncthreads();
#pragma unroll
  for (int q = 0; q < 4; ++q) {
    int dr = lr + q * 8;
    float v = t[lc][dr];
    unsigned short h = f2bf(v);
    unsigned short l = f2bf(v - bf2f(h));
    size_t o = (size_t)(bc + dr) * ldd + roff + br + lc;
    dhi[o] = h;
    dlo[o] = l;
  }
}

// [Wu|Uu; Wr|Ur; Wh|0] -> hi/lo row-major [3d][2d]
__device__ __forceinline__ void d_catsplit(int blk, int d, const float* __restrict__ Wu,
                                           const float* __restrict__ Uu,
                                           const float* __restrict__ Wr,
                                           const float* __restrict__ Ur,
                                           const float* __restrict__ Wh,
                                           unsigned short* __restrict__ hi,
                                           unsigned short* __restrict__ lo) {
  int idx = blk * 256 + threadIdx.x;
  int K = 2 * d;
  if (idx >= 3 * d * K) return;
  int row = idx / K, col = idx - row * K;
  int reg = row / d;
  int i = row - reg * d;
  float v;
  if (reg == 0) v = (col < d) ? Wu[i * d + col] : Uu[i * d + col - d];
  else if (reg == 1) v = (col < d) ? Wr[i * d + col] : Ur[i * d + col - d];
  else v = (col < d) ? Wh[i * d + col] : 0.f;
  unsigned short h = f2bf(v);
  hi[idx] = h;
  lo[idx] = f2bf(v - bf2f(h));
}

__device__ __forceinline__ void d_split(int blk, int n, const float* __restrict__ src,
                                        unsigned short* __restrict__ hi,
                                        unsigned short* __restrict__ lo) {
  int idx = blk * 256 + threadIdx.x;
  if (idx >= n) return;
  float v = src[idx];
  unsigned short h = f2bf(v);
  hi[idx] = h;
  lo[idx] = f2bf(v - bf2f(h));
}

// One dispatcher kernel for all startup work (was 11 dispatches).
__global__ __launch_bounds__(256) void k_startup(
    const float* __restrict__ scorer0, const float* __restrict__ scorer1,
    float* __restrict__ ctlf,
    const float* __restrict__ mlpW1, unsigned short* __restrict__ mW1thi,
    unsigned short* __restrict__ mW1tlo,
    const float* __restrict__ gcnW0, const float* __restrict__ gcnW1,
    unsigned short* __restrict__ bt0hi, unsigned short* __restrict__ bt0lo,
    unsigned short* __restrict__ bt1hi, unsigned short* __restrict__ bt1lo,
    const float* __restrict__ u_W0, const float* __restrict__ u_U0,
    const float* __restrict__ r_W0, const float* __restrict__ r_U0,
    const float* __restrict__ h_W0,
    unsigned short* __restrict__ acat0hi, unsigned short* __restrict__ acat0lo,
    const float* __restrict__ u_W1, const float* __restrict__ u_U1,
    const float* __restrict__ r_W1, const float* __restrict__ r_U1,
    const float* __restrict__ h_W1,
    unsigned short* __restrict__ acat1hi, unsigned short* __restrict__ acat1lo,
    const float* __restrict__ uh0, unsigned short* __restrict__ uh0hi,
    unsigned short* __restrict__ uh0lo,
    const float* __restrict__ uh1, unsigned short* __restrict__ uh1hi,
    unsigned short* __restrict__ uh1lo,
    float* __restrict__ Q0, float* __restrict__ Q1,
    unsigned int* __restrict__ bar) {
  __shared__ float red[256];
  __shared__ float tile[32][33];
  int b = blockIdx.x;
  if (b == SU_NORM0) { d_norm(scorer0, FD, ctlf, C_NORM0, red); return; }
  if (b == SU_NORM1) { d_norm(scorer1, HD, ctlf, C_NORM1, red); return; }
  if (b < SU_CVT_B) { int r = b - SU_CVT_A; d_cvtT(r & 15, r >> 4, mlpW1, CH, mW1thi, mW1tlo, HD, 0, tile); return; }
  if (b < SU_CVT_C) { int r = b - SU_CVT_B; d_cvtT(r & 3, r >> 2, gcnW0, HD, bt0hi, bt0lo, 2 * FD, FD, tile); return; }
  if (b < SU_CAT0)  { int r = b - SU_CVT_C; d_cvtT(r & 3, r >> 2, gcnW1, HD, bt1hi, bt1lo, 2 * HD, HD, tile); return; }
  if (b < SU_CAT1)  { d_catsplit(b - SU_CAT0, FD, u_W0, u_U0, r_W0, r_U0, h_W0, acat0hi, acat0lo); return; }
  if (b < SU_SPL0)  { d_catsplit(b - SU_CAT1, HD, u_W1, u_U1, r_W1, r_U1, h_W1, acat1hi, acat1lo); return; }
  if (b < SU_SPL1)  { d_split(b - SU_SPL0, FD * FD, uh0, uh0hi, uh0lo); return; }
  if (b < SU_CPQ0)  { d_split(b - SU_SPL1, HD * HD, uh1, uh1hi, uh1lo); return; }
  if (b < SU_CPQ1)  { int i = (b - SU_CPQ0) * 256 + threadIdx.x; ((float4*)Q0)[i] = ((const float4*)gcnW0)[i]; return; }
  if (b < SU_ZBAR)  { int i = (b - SU_CPQ1) * 256 + threadIdx.x; ((float4*)Q1)[i] = ((const float4*)gcnW1)[i]; return; }
  if (threadIdx.x < 16) bar[threadIdx.x] = 0;
}

// ---- graph build (LDS histogram CSR, no global atomics) ----
__global__ __launch_bounds__(1024) void k_degC(const int* __restrict__ edges,
                                               unsigned int* __restrict__ chist) {
  __shared__ unsigned int lcnt[WPH];
  int t = blockIdx.y, c = blockIdx.x;
  int tid = threadIdx.x;
  for (int dir = 0; dir < 2; ++dir) {
    const int* E = edges + (size_t)t * 2 * NE + (size_t)dir * NE + (size_t)c * CHE;
    for (int half = 0; half < 2; ++half) {
      for (int i = tid; i < WPH; i += 1024) lcnt[i] = 0;
      __syncthreads();
      int lo = half * HALFN;
      for (int j = tid; j < CHE; j += 1024) {
        int n = E[j] - lo;
        if ((unsigned)n < (unsigned)HALFN)
          atomicAdd(&lcnt[n >> 1], 1u << ((n & 1) * 16));
      }
      __syncthreads();
      unsigned int* dst = chist + (((size_t)dir * NT + t) * NCH + c) * WPC + (size_t)half * WPH;
      for (int i = tid; i < WPH; i += 1024) dst[i] = lcnt[i];
      __syncthreads();
    }
  }
}

__global__ __launch_bounds__(1024) void k_scanB(const unsigned int* __restrict__ chist,
                                                unsigned int* __restrict__ lbase,
                                                float* __restrict__ dor4,
                                                float* __restrict__ din4,
                                                int* __restrict__ rowptr4,
                                                int* __restrict__ bsum4) {
  int t = blockIdx.y;
  int tid = threadIdx.x;
  int g = blockIdx.x * 1024 + tid;
  int lane = tid & 63, wid = tid >> 6;
  int v = 0;
  if (g < NN) {
    int w = g >> 1, sh = (g & 1) * 16;
    const unsigned int* oh = chist + ((size_t)0 * NT + t) * NCH * WPC;
    const unsigned int* ih = chist + ((size_t)1 * NT + t) * NCH * WPC;
    int o = 0;
#pragma unroll
    for (int c = 0; c < NCH; ++c) o += (oh[(size_t)c * WPC + w] >> sh) & 0xffff;
    dor4[t * NN + g] = 1.f / sqrtf((float)max(o, 1));
    int run = 0;
#pragma unroll
    for (int c = 0; c < NCH; ++c) {
      lbase[((size_t)t * NCH + c) * NN + g] = (unsigned int)run;
      run += (ih[(size_t)c * WPC + w] >> sh) & 0xffff;
    }
    v = run;
    din4[t * NN + g] = 1.f / sqrtf((float)max(v, 1));
  }
  int s = v;
  for (int o = 1; o < 64; o <<= 1) {
    int u = __shfl_up(s, o, 64);
    if (lane >= o) s += u;
  }
  __shared__ int ws[16];
  if (lane == 63) ws[wid] = s;
  __syncthreads();
  if (wid == 0 && lane < 16) {
    int u = ws[lane];
    int ss = u;
    for (int o = 1; o < 16; o <<= 1) {
      int w2 = __shfl_up(ss, o, 64);
      if (lane >= o) ss += w2;
    }
    ws[lane] = ss - u;
  }
  __syncthreads();
  int incl = s + ws[wid];
  if (g < NN) rowptr4[(size_t)t * (NN + 1) + g] = incl - v;
  if (tid == 1023) bsum4[t * SCAN_BLOCKS + blockIdx.x] = incl;
}

__global__ __launch_bounds__(1024) void k_scan2b(int* __restrict__ rowptr4,
                                                 const int* __restrict__ bsum4) {
  int t = blockIdx.x;
  int* rowptr = rowptr4 + (size_t)t * (NN + 1);
  const int* bsum = bsum4 + t * SCAN_BLOCKS;
  __shared__ int boff[SCAN_BLOCKS];
  __shared__ int total;
  int tid = threadIdx.x;
  if (tid < 64) {
    int v = (tid < SCAN_BLOCKS) ? bsum[tid] : 0;
    int s = v;
    for (int o = 1; o < 64; o <<= 1) {
      int u = __shfl_up(s, o, 64);
      if (tid >= o) s += u;
    }
    if (tid < SCAN_BLOCKS) boff[tid] = s - v;
    if (tid == SCAN_BLOCKS - 1) total = s;
  }
  __syncthreads();
  for (int i = tid; i < NN; i += 1024) rowptr[i] += boff[i >> 10];
  if (tid == 0) rowptr[NN] = total;
}

__global__ __launch_bounds__(1024) void k_scatC(const int* __restrict__ edges,
                                                const int* __restrict__ rowptr4,
                                                const unsigned int* __restrict__ lbase,
                                                int* __restrict__ srcs4) {
  __shared__ unsigned int lcnt[WPH];
  int t = blockIdx.y, c = blockIdx.x;
  int tid = threadIdx.x;
  const int* srcE = edges + (size_t)t * 2 * NE + (size_t)c * CHE;
  const int* dstE = srcE + NE;
  const int* rowptr = rowptr4 + (size_t)t * (NN + 1);
  const unsigned int* lb = lbase + ((size_t)t * NCH + c) * NN;
  int* srcs = srcs4 + (size_t)t * NE;
  for (int half = 0; half < 2; ++half) {
    for (int i = tid; i < WPH; i += 1024) lcnt[i] = 0;
    __syncthreads();
    int lo = half * HALFN;
    for (int j = tid; j < CHE; j += 1024) {
      int d = dstE[j];
      int n = d - lo;
      if ((unsigned)n < (unsigned)HALFN) {
        unsigned int old = atomicAdd(&lcnt[n >> 1], 1u << ((n & 1) * 16));
        int ord = (int)((old >> ((n & 1) * 16)) & 0xffff);
        int pos = rowptr[d] + (int)lb[d] + ord;
        srcs[pos] = srcE[j];
      }
    }
    __syncthreads();
  }
}

// ---- layer-0 scores (read-only over feats) ----
__global__ void k_scores0_all(const float* __restrict__ feats, const float* __restrict__ sc,
                              const float* __restrict__ ctlf, float* __restrict__ scores0) {
  int t = blockIdx.y;
  int w = (blockIdx.x * blockDim.x + threadIdx.x) >> 6;
  int lane = threadIdx.x & 63;
  if (w >= NN) return;
  size_t rowoff = ((size_t)t * NN + w) * FD;
  float4 x = *(const float4*)(feats + rowoff + lane * 4);
  float4 s = *(const float4*)(sc + lane * 4);
  double acc = (double)x.x * s.x + (double)x.y * s.y + (double)x.z * s.z + (double)x.w * s.w;
  for (int m = 32; m > 0; m >>= 1) acc += __shfl_xor(acc, m, 64);
  if (lane == 0) scores0[(size_t)t * NN + w] = (float)(acc / (double)ctlf[C_NORM0]);
}

// Fused top-k pool: LDS hist -> threshold -> gather -> bitonic -> z^T hi/lo
template <int LOGD>
__global__ __launch_bounds__(1024) void k_pool(const float* __restrict__ Xb, long xStride,
                                               const float* __restrict__ scoresB, int sStride,
                                               unsigned short* __restrict__ bthiB,
                                               unsigned short* __restrict__ btloB,
                                               long btStride, int ldb) {
  const int D = 1 << LOGD;
  int t = blockIdx.x;
  const float* X = Xb + (size_t)t * xStride;
  const float* scores = scoresB + (size_t)t * sStride;
  unsigned short* bthi = bthiB + (size_t)t * btStride;
  unsigned short* btlo = btloB + (size_t)t * btStride;
  __shared__ int hist[NBINS];
  __shared__ int sufT[1024];
  __shared__ float cs[CAPC];
  __shared__ int ci[CAPC];
  __shared__ float stv[HD];
  __shared__ int sidx[HD];
  __shared__ int thrBin, cnt;
  int tid = threadIdx.x;
  for (int i = tid; i < NBINS; i += 1024) hist[i] = 0;
  if (tid == 0) cnt = 0;
  __syncthreads();
  for (int i = tid; i < NN; i += 1024) atomicAdd(&hist[sbin(scores[i])], 1);
  __syncthreads();

  int h0 = hist[4 * tid + 0], h1 = hist[4 * tid + 1];
  int h2 = hist[4 * tid + 2], h3 = hist[4 * tid + 3];
  int l3 = h3, l2 = h2 + l3, l1 = h1 + l2, l0 = h0 + l1;
  sufT[tid] = l0;
  __syncthreads();
  for (int off = 1; off < 1024; off <<= 1) {
    int u = (tid + off < 1024) ? sufT[tid + off] : 0;
    __syncthreads();
    sufT[tid] += u;
    __syncthreads();
  }
  {
    int higher = sufT[tid] - l0;
    int S0 = l0 + higher, S1 = l1 + higher, S2 = l2 + higher, S3 = l3 + higher;
    int S4 = higher;
    if (S3 >= HD && S4 < HD) thrBin = 4 * tid + 3;
    else if (S2 >= HD && S3 < HD) thrBin = 4 * tid + 2;
    else if (S1 >= HD && S2 < HD) thrBin = 4 * tid + 1;
    else if (S0 >= HD && S1 < HD) thrBin = 4 * tid + 0;
  }
  __syncthreads();
  int thr = thrBin;
  for (int i = tid; i < NN; i += 1024) {
    float s = scores[i];
    if (sbin(s) >= thr) {
      int p = atomicAdd(&cnt, 1);
      if (p < CAPC) { cs[p] = s; ci[p] = i; }
    }
  }
  __syncthreads();
  int M = min(cnt, CAPC);
  for (int i = tid; i < CAPC; i += 1024)
    if (i >= M) { cs[i] = -3.4e38f; ci[i] = 0x7fffffff; }
  __syncthreads();
  for (int k = 2; k <= CAPC; k <<= 1) {
    for (int j = k >> 1; j > 0; j >>= 1) {
      int i = tid;
      if (i < CAPC) {
        int l = i ^ j;
        if (l > i) {
          float si = cs[i], sl = cs[l];
          int di = ci[i], dl = ci[l];
          bool lb = (sl > si) || (sl == si && dl < di);
          bool ib = (si > sl) || (si == sl && di < dl);
          bool dir = ((i & k) == 0);
          if (dir ? lb : ib) {
            cs[i] = sl; cs[l] = si; ci[i] = dl; ci[l] = di;
          }
        }
      }
      __syncthreads();
    }
  }
  if (tid < HD) {
    stv[tid] = tanhf(cs[tid]);
    sidx[tid] = ci[tid];
  }
  __syncthreads();
  for (int e4 = tid * 4; e4 < D * HD; e4 += 1024 * 4) {
    int j = e4 >> LOGD, f = e4 & (D - 1);
    float4 x = *(const float4*)&X[(size_t)sidx[j] * D + f];
    float sv = stv[j];
    x.x *= sv; x.y *= sv; x.z *= sv; x.w *= sv;
    ushort4 h, l;
    h.x = f2bf(x.x); l.x = f2bf(x.x - bf2f(h.x));
    h.y = f2bf(x.y); l.y = f2bf(x.y - bf2f(h.y));
    h.z = f2bf(x.z); l.z = f2bf(x.z - bf2f(h.z));
    h.w = f2bf(x.w); l.w = f2bf(x.w - bf2f(h.w));
    *(ushort4*)&bthi[(size_t)j * ldb + f] = h;
    *(ushort4*)&btlo[(size_t)j * ldb + f] = l;
  }
}

// ---- GRU phase A body: [Wu|Uu; Wr|Ur; Wh|0] @ [z;Q] -> u, rqT(hi/lo), hz ----
__device__ __forceinline__ void gruA_body(
    int bx, const unsigned short* __restrict__ Ahi, const unsigned short* __restrict__ Alo,
    const unsigned short* __restrict__ Bhi, const unsigned short* __restrict__ Blo,
    int d, const float* __restrict__ bu, const float* __restrict__ br,
    const float* __restrict__ bh, const float* __restrict__ Q,
    float* __restrict__ u, float* __restrict__ hz,
    unsigned short* __restrict__ rqThi, unsigned short* __restrict__ rqTlo,
    unsigned short* AshH, unsigned short* AshL,
    unsigned short* BshH, unsigned short* BshL) {
  int K = 2 * d;
  int tid = threadIdx.x;
  int lane = tid & 63, wave = tid >> 6;
  int wr = wave >> 1, wc = wave & 1;
  int n0 = bx * 64;
  f32x4 acc[2][4];
#pragma unroll
  for (int m = 0; m < 2; ++m)
#pragma unroll
    for (int n = 0; n < 4; ++n) acc[m][n] = (f32x4){0.f, 0.f, 0.f, 0.f};
  int arow = tid >> 2, aseg = tid & 3;
  int as = (aseg ^ (arow & 3)) * 8;
  int kseg = lane >> 4;
  for (int k0 = 0; k0 < K; k0 += 32) {
    __syncthreads();
    {
      size_t off = (size_t)(n0 + arow) * K + k0 + aseg * 8;
      *(bf16x8*)&AshH[arow * 32 + as] = *(const bf16x8*)(Ahi + off);
      *(bf16x8*)&AshL[arow * 32 + as] = *(const bf16x8*)(Alo + off);
    }
#pragma unroll
    for (int h = 0; h < 2; ++h) {
      int id = tid + h * 256;
      int br2 = id >> 2, bseg = id & 3;
      int bs = (bseg ^ (br2 & 3)) * 8;
      size_t off = (size_t)br2 * K + k0 + bseg * 8;
      *(bf16x8*)&BshH[br2 * 32 + bs] = *(const bf16x8*)(Bhi + off);
      *(bf16x8*)&BshL[br2 * 32 + bs] = *(const bf16x8*)(Blo + off);
    }
    __syncthreads();
    bf16x8 ah[2], al[2], bh8[4], bl8[4];
#pragma unroll
    for (int m = 0; m < 2; ++m) {
      int row = wr * 32 + m * 16 + (lane & 15);
      int s = (kseg ^ (row & 3)) * 8;
      ah[m] = *(bf16x8*)&AshH[row * 32 + s];
      al[m] = *(bf16x8*)&AshL[row * 32 + s];
    }
#pragma unroll
    for (int n = 0; n < 4; ++n) {
      int col = wc * 64 + n * 16 + (lane & 15);
      int s = (kseg ^ (col & 3)) * 8;
      bh8[n] = *(bf16x8*)&BshH[col * 32 + s];
      bl8[n] = *(bf16x8*)&BshL[col * 32 + s];
    }
#pragma unroll
    for (int m = 0; m < 2; ++m)
#pragma unroll
      for (int n = 0; n < 4; ++n) {
        acc[m][n] = __builtin_amdgcn_mfma_f32_16x16x32_bf16(ah[m], bh8[n], acc[m][n], 0, 0, 0);
        acc[m][n] = __builtin_amdgcn_mfma_f32_16x16x32_bf16(al[m], bh8[n], acc[m][n], 0, 0, 0);
        acc[m][n] = __builtin_amdgcn_mfma_f32_16x16x32_bf16(ah[m], bl8[n], acc[m][n], 0, 0, 0);
      }
  }
  int reg = n0 / d;
#pragma unroll
  for (int m = 0; m < 2; ++m) {
#pragma unroll
    for (int q = 0; q < 4; ++q) {
      int row = n0 + wr * 32 + m * 16 + (lane >> 4) * 4 + q;
      int i = row - reg * d;
#pragma unroll
      for (int n = 0; n < 4; ++n) {
        int col = wc * 64 + n * 16 + (lane & 15);
        float a = acc[m][n][q];
        if (reg == 0) {
          u[i * HD + col] = 1.f / (1.f + expf(-(a + bu[i * HD + col])));
        } else if (reg == 1) {
          float r = 1.f / (1.f + expf(-(a + br[i * HD + col])));
          float rq = r * Q[i * HD + col];
          unsigned short h = f2bf(rq);
          rqThi[(size_t)col * d + i] = h;
          rqTlo[(size_t)col * d + i] = f2bf(rq - bf2f(h));
        } else {
          hz[i * HD + col] = a + bh[i * HD + col];
        }
      }
    }
  }
}

// ---- GRU phase B body: Uh @ rQ; epilogue: W' = (1-u)Q + u*tanh(hz+acc); in-place Q ----
__device__ __forceinline__ void gruB_body(
    int bx, const unsigned short* __restrict__ Ahi, const unsigned short* __restrict__ Alo,
    const unsigned short* __restrict__ Bhi, const unsigned short* __restrict__ Blo,
    int d, const float* __restrict__ hz, const float* __restrict__ u,
    float* __restrict__ Q, unsigned short* __restrict__ BTWhi,
    unsigned short* __restrict__ BTWlo, int ldbt,
    unsigned short* AshH, unsigned short* AshL,
    unsigned short* BshH, unsigned short* BshL) {
  int K = d;
  int tid = threadIdx.x;
  int lane = tid & 63, wave = tid >> 6;
  int wr = wave >> 1, wc = wave & 1;
  int n0 = bx * 64;
  f32x4 acc[2][4];
#pragma unroll
  for (int m = 0; m < 2; ++m)
#pragma unroll
    for (int n = 0; n < 4; ++n) acc[m][n] = (f32x4){0.f, 0.f, 0.f, 0.f};
  int arow = tid >> 2, aseg = tid & 3;
  int as = (aseg ^ (arow & 3)) * 8;
  int kseg = lane >> 4;
  for (int k0 = 0; k0 < K; k0 += 32) {
    __syncthreads();
    {
      size_t off = (size_t)(n0 + arow) * K + k0 + aseg * 8;
      *(bf16x8*)&AshH[arow * 32 + as] = *(const bf16x8*)(Ahi + off);
      *(bf16x8*)&AshL[arow * 32 + as] = *(const bf16x8*)(Alo + off);
    }
#pragma unroll
    for (int h = 0; h < 2; ++h) {
      int id = tid + h * 256;
      int br2 = id >> 2, bseg = id & 3;
      int bs = (bseg ^ (br2 & 3)) * 8;
      size_t off = (size_t)br2 * K + k0 + bseg * 8;
      *(bf16x8*)&BshH[br2 * 32 + bs] = *(const bf16x8*)(Bhi + off);
      *(bf16x8*)&BshL[br2 * 32 + bs] = *(const bf16x8*)(Blo + off);
    }
    __syncthreads();
    bf16x8 ah[2], al[2], bh8[4], bl8[4];
#pragma unroll
    for (int m = 0; m < 2; ++m) {
      int row = wr * 32 + m * 16 + (lane & 15);
      int s = (kseg ^ (row & 3)) * 8;
      ah[m] = *(bf16x8*)&AshH[row * 32 + s];
      al[m] = *(bf16x8*)&AshL[row * 32 + s];
    }
#pragma unroll
    for (int n = 0; n < 4; ++n) {
      int col = wc * 64 + n * 16 + (lane & 15);
      int s = (kseg ^ (col & 3)) * 8;
      bh8[n] = *(bf16x8*)&BshH[col * 32 + s];
      bl8[n] = *(bf16x8*)&BshL[col * 32 + s];
    }
#pragma unroll
    for (int m = 0; m < 2; ++m)
#pragma unroll
      for (int n = 0; n < 4; ++n) {
        acc[m][n] = __builtin_amdgcn_mfma_f32_16x16x32_bf16(ah[m], bh8[n], acc[m][n], 0, 0, 0);
        acc[m][n] = __builtin_amdgcn_mfma_f32_16x16x32_bf16(al[m], bh8[n], acc[m][n], 0, 0, 0);
        acc[m][n] = __builtin_amdgcn_mfma_f32_16x16x32_bf16(ah[m], bl8[n], acc[m][n], 0, 0, 0);
      }
  }
#pragma unroll
  for (int m = 0; m < 2; ++m) {
#pragma unroll
    for (int q = 0; q < 4; ++q) {
      int i = n0 + wr * 32 + m * 16 + (lane >> 4) * 4 + q;
#pragma unroll
      for (int n = 0; n < 4; ++n) {
        int col = wc * 64 + n * 16 + (lane & 15);
        float hc = tanhf(acc[m][n][q] + hz[i * HD + col]);
        float uu = u[i * HD + col];
        float qv = Q[i * HD + col];
        float wn = (1.f - uu) * qv + uu * hc;
        Q[i * HD + col] = wn;
        unsigned short h = f2bf(wn);
        BTWhi[(size_t)col * ldbt + i] = h;
        BTWlo[(size_t)col * ldbt + i] = f2bf(wn - bf2f(h));
      }
    }
  }
}

// Persistent 4-step GRU chain (replaces 8 launches). grid = 3*d/64 blocks.
// Device barrier between phase A and phase B and between steps.
__global__ __launch_bounds__(256) void k_gruChain(
    const unsigned short* __restrict__ Ahi, const unsigned short* __restrict__ Alo,
    unsigned short* __restrict__ bthi, unsigned short* __restrict__ btlo, long btSz,
    int d, const float* __restrict__ gb_u, const float* __restrict__ gb_r,
    const float* __restrict__ gb_h, float* __restrict__ Q,
    float* __restrict__ ubuf, float* __restrict__ hzbuf,
    unsigned short* __restrict__ rqThi, unsigned short* __restrict__ rqTlo,
    const unsigned short* __restrict__ uhhi, const unsigned short* __restrict__ uhlo,
    unsigned int* bar) {
  __shared__ unsigned short AshH[64 * 32], AshL[64 * 32];
  __shared__ unsigned short BshH[128 * 32], BshL[128 * 32];
  int nb = (int)gridDim.x;
  for (int t = 0; t < NT; ++t) {
    gruA_body((int)blockIdx.x, Ahi, Alo,
              bthi + (size_t)t * btSz, btlo + (size_t)t * btSz, d,
              gb_u, gb_r, gb_h, Q, ubuf, hzbuf, rqThi, rqTlo,
              AshH, AshL, BshH, BshL);
    gbar(bar, nb, 2 * t);
    if ((int)blockIdx.x < (d >> 6)) {
      size_t nxt = (size_t)((t + 1) & 3) * btSz;
      gruB_body((int)blockIdx.x, uhhi, uhlo, rqThi, rqTlo, d, hzbuf, ubuf, Q,
                bthi + nxt + d, btlo + nxt + d, 2 * d,
                AshH, AshL, BshH, BshL);
    }
    if (t < NT - 1) gbar(bar, nb, 2 * t + 1);
  }
}

// Batched layer-0 conv: blockIdx.z = t. C4[t] = (feats[t] @ W^T(t)) * dor4[t].
__global__ __launch_bounds__(256) void k_convL0(
    const float* __restrict__ feats,
    const unsigned short* __restrict__ bt0hi, const unsigned short* __restrict__ bt0lo,
    float* __restrict__ C4, const float* __restrict__ dor4) {
  __shared__ unsigned short AshH[64 * 32], AshL[64 * 32];
  __shared__ unsigned short BshH[128 * 32], BshL[128 * 32];
  const int K = FD, ldb = 2 * FD;
  int t = blockIdx.z;
  const float* Af = feats + (size_t)t * NN * FD;
  size_t bOff = (size_t)((t + 1) & 3) * BT0SZ + FD;
  const unsigned short* Bhi = bt0hi + bOff;
  const unsigned short* Blo = bt0lo + bOff;
  float* C = C4 + (size_t)t * NN * HD;
  const float* rs = dor4 + (size_t)t * NN;
  int tid = threadIdx.x;
  int lane = tid & 63, wave = tid >> 6;
  int wr = wave >> 1, wc = wave & 1;
  int n0 = blockIdx.x * 64;
  f32x4 acc[2][4];
#pragma unroll
  for (int m = 0; m < 2; ++m)
#pragma unroll
    for (int n = 0; n < 4; ++n) acc[m][n] = (f32x4){0.f, 0.f, 0.f, 0.f};

  int arow = tid >> 2, aseg = tid & 3;
  int as = (aseg ^ (arow & 3)) * 8;
  int kseg = lane >> 4;

  for (int k0 = 0; k0 < K; k0 += 32) {
    __syncthreads();
    {
      bf16x8 vh = (bf16x8)(short)0, vl = (bf16x8)(short)0;
      int row = n0 + arow;
      if (row < NN) {
        const float* g = Af + (size_t)row * K + k0 + aseg * 8;
        float4 v0 = *(const float4*)g;
        float4 v1 = *(const float4*)(g + 4);
        float xs[8] = {v0.x, v0.y, v0.z, v0.w, v1.x, v1.y, v1.z, v1.w};
#pragma unroll
        for (int j = 0; j < 8; ++j) {
          unsigned short h = f2bf(xs[j]);
          vh[j] = (short)h;
          vl[j] = (short)f2bf(xs[j] - bf2f(h));
        }
      }
      *(bf16x8*)&AshH[arow * 32 + as] = vh;
      *(bf16x8*)&AshL[arow * 32 + as] = vl;
    }
#pragma unroll
    for (int h = 0; h < 2; ++h) {
      int id = tid + h * 256;
      int br = id >> 2, bseg = id & 3;
      int bs = (bseg ^ (br & 3)) * 8;
      size_t off = (size_t)br * ldb + k0 + bseg * 8;
      *(bf16x8*)&BshH[br * 32 + bs] = *(const bf16x8*)(Bhi + off);
      *(bf16x8*)&BshL[br * 32 + bs] = *(const bf16x8*)(Blo + off);
    }
    __syncthreads();

    bf16x8 ah[2], al[2], bh[4], bl[4];
#pragma unroll
    for (int m = 0; m < 2; ++m) {
      int row = wr * 32 + m * 16 + (lane & 15);
      int s = (kseg ^ (row & 3)) * 8;
      ah[m] = *(bf16x8*)&AshH[row * 32 + s];
      al[m] = *(bf16x8*)&AshL[row * 32 + s];
    }
#pragma unroll
    for (int n = 0; n < 4; ++n) {
      int col = wc * 64 + n * 16 + (lane & 15);
      int s = (kseg ^ (col & 3)) * 8;
      bh[n] = *(bf16x8*)&BshH[col * 32 + s];
      bl[n] = *(bf16x8*)&BshL[col * 32 + s];
    }
#pragma unroll
    for (int m = 0; m < 2; ++m)
#pragma unroll
      for (int n = 0; n < 4; ++n) {
        acc[m][n] = __builtin_amdgcn_mfma_f32_16x16x32_bf16(ah[m], bh[n], acc[m][n], 0, 0, 0);
        acc[m][n] = __builtin_amdgcn_mfma_f32_16x16x32_bf16(al[m], bh[n], acc[m][n], 0, 0, 0);
        acc[m][n] = __builtin_amdgcn_mfma_f32_16x16x32_bf16(ah[m], bl[n], acc[m][n], 0, 0, 0);
      }
  }

#pragma unroll
  for (int m = 0; m < 2; ++m) {
#pragma unroll
    for (int q = 0; q < 4; ++q) {
      int row = n0 + wr * 32 + m * 16 + (lane >> 4) * 4 + q;
      if (row >= NN) continue;
      float rsv = rs[row];
#pragma unroll
      for (int n = 0; n < 4; ++n) {
        int col = wc * 64 + n * 16 + (lane & 15);
        C[(size_t)row * HD + col] = acc[m][n][q] * rsv;
      }
    }
  }
}

// L1 conv (single t): A = bf16 hi/lo pair.
__global__ __launch_bounds__(256) void k_gemm3(
    const unsigned short* __restrict__ Ahi, const unsigned short* __restrict__ Alo, int lda,
    const unsigned short* __restrict__ Bhi, const unsigned short* __restrict__ Blo, int ldb,
    float* __restrict__ C, int ldo, int M, int K,
    const float* __restrict__ rs) {
  __shared__ unsigned short AshH[64 * 32], AshL[64 * 32];
  __shared__ unsigned short BshH[128 * 32], BshL[128 * 32];
  int tid = threadIdx.x;
  int lane = tid & 63, wave = tid >> 6;
  int wr = wave >> 1, wc = wave & 1;
  int n0 = blockIdx.x * 64;
  int c0 = blockIdx.y * 128;
  f32x4 acc[2][4];
#pragma unroll
  for (int m = 0; m < 2; ++m)
#pragma unroll
    for (int n = 0; n < 4; ++n) acc[m][n] = (f32x4){0.f, 0.f, 0.f, 0.f};

  int arow = tid >> 2, aseg = tid & 3;
  int as = (aseg ^ (arow & 3)) * 8;
  int kseg = lane >> 4;

  for (int k0 = 0; k0 < K; k0 += 32) {
    __syncthreads();
    {
      bf16x8 vh = (bf16x8)(short)0, vl = (bf16x8)(short)0;
      int row = n0 + arow;
      if (row < M) {
        size_t off = (size_t)row * lda + k0 + aseg * 8;
        vh = *(const bf16x8*)(Ahi + off);
        vl = *(const bf16x8*)(Alo + off);
      }
      *(bf16x8*)&AshH[arow * 32 + as] = vh;
      *(bf16x8*)&AshL[arow * 32 + as] = vl;
    }
#pragma unroll
    for (int h = 0; h < 2; ++h) {
      int id = tid + h * 256;
      int br = id >> 2, bseg = id & 3;
      int bs = (bseg ^ (br & 3)) * 8;
      size_t off = (size_t)(c0 + br) * ldb + k0 + bseg * 8;
      *(bf16x8*)&BshH[br * 32 + bs] = *(const bf16x8*)(Bhi + off);
      *(bf16x8*)&BshL[br * 32 + bs] = *(const bf16x8*)(Blo + off);
    }
    __syncthreads();

    bf16x8 ah[2], al[2], bh[4], bl[4];
#pragma unroll
    for (int m = 0; m < 2; ++m) {
      int row = wr * 32 + m * 16 + (lane & 15);
      int s = (kseg ^ (row & 3)) * 8;
      ah[m] = *(bf16x8*)&AshH[row * 32 + s];
      al[m] = *(bf16x8*)&AshL[row * 32 + s];
    }
#pragma unroll
    for (int n = 0; n < 4; ++n) {
      int col = wc * 64 + n * 16 + (lane & 15);
      int s = (kseg ^ (col & 3)) * 8;
      bh[n] = *(bf16x8*)&BshH[col * 32 + s];
      bl[n] = *(bf16x8*)&BshL[col * 32 + s];
    }
#pragma unroll
    for (int m = 0; m < 2; ++m)
#pragma unroll
      for (int n = 0; n < 4; ++n) {
        acc[m][n] = __builtin_amdgcn_mfma_f32_16x16x32_bf16(ah[m], bh[n], acc[m][n], 0, 0, 0);
        acc[m][n] = __builtin_amdgcn_mfma_f32_16x16x32_bf16(al[m], bh[n], acc[m][n], 0, 0, 0);
        acc[m][n] = __builtin_amdgcn_mfma_f32_16x16x32_bf16(ah[m], bl[n], acc[m][n], 0, 0, 0);
      }
  }

#pragma unroll
  for (int m = 0; m < 2; ++m) {
#pragma unroll
    for (int q = 0; q < 4; ++q) {
      int row = n0 + wr * 32 + m * 16 + (lane >> 4) * 4 + q;
      if (row >= M) continue;
      float rsv = rs[row];
#pragma unroll
      for (int n = 0; n < 4; ++n) {
        int col = c0 + wc * 64 + n * 16 + (lane & 15);
        C[(size_t)row * ldo + col] = acc[m][n][q] * rsv;
      }
    }
  }
}

// Fused final aggregate + MLP head: A-tile is aggregated in-staging from hbuf
// (replaces k_aggF + k_gemmMLP; kills the 51 MB fahi/falo round-trip and lets
// the gather latency hide under MFMA across blocks).
__global__ __launch_bounds__(256) void k_gemmMLPagg(
    const float* __restrict__ h, const int* __restrict__ rowptr,
    const int* __restrict__ srcs, const float* __restrict__ din,
    const unsigned short* __restrict__ Bhi, const unsigned short* __restrict__ Blo,
    const float* __restrict__ bias, const float* __restrict__ W2,
    const float* __restrict__ b2, float* __restrict__ out, int M) {
  __shared__ unsigned short AshH[64 * 128], AshL[64 * 128];
  __shared__ unsigned short BshH[128 * 32], BshL[128 * 32];
  __shared__ float osum[64][2];
  int tid = threadIdx.x;
  int lane = tid & 63, wave = tid >> 6;
  int wr = wave >> 1, wc = wave & 1;
  int n0 = blockIdx.x * 64;
  if (tid < 128) ((float*)osum)[tid] = 0.f;

  {
    // aggregate 64 rows: 4 threads per row, 32 cols each
    int row = tid >> 2, seg = tid & 3;
    int grow = n0 + row;
    float a[32];
#pragma unroll
    for (int i = 0; i < 32; ++i) a[i] = 0.f;
    if (grow < M) {
      int beg = rowptr[grow], end = rowptr[grow + 1];
      int c0 = seg * 32;
      for (int e = beg; e < end; ++e) {
        const float* hr = h + (size_t)srcs[e] * HD + c0;
#pragma unroll
        for (int i = 0; i < 8; ++i) {
          float4 v = *(const float4*)(hr + i * 4);
          a[i * 4 + 0] += v.x; a[i * 4 + 1] += v.y;
          a[i * 4 + 2] += v.z; a[i * 4 + 3] += v.w;
        }
      }
      float dn = din[grow];
#pragma unroll
      for (int i = 0; i < 32; ++i) {
        float v = a[i] * dn;
        a[i] = v >= 0.f ? v : RSLOPE * v;
      }
    }
#pragma unroll
    for (int q = 0; q < 4; ++q) {
      int s = seg * 4 + q;
      bf16x8 vh, vl;
#pragma unroll
      for (int j = 0; j < 8; ++j) {
        float v = a[q * 8 + j];
        unsigned short hh = f2bf(v);
        vh[j] = (short)hh;
        vl[j] = (short)f2bf(v - bf2f(hh));
      }
      int sp = (s ^ (row & 15)) * 8;
      *(bf16x8*)&AshH[row * 128 + sp] = vh;
      *(bf16x8*)&AshL[row * 128 + sp] = vl;
    }
  }
  __syncthreads();

  float ps0[2][4], ps1[2][4];
#pragma unroll
  for (int m = 0; m < 2; ++m)
#pragma unroll
    for (int q = 0; q < 4; ++q) { ps0[m][q] = 0.f; ps1[m][q] = 0.f; }

  int kseg = lane >> 4;
  for (int hc = 0; hc < 4; ++hc) {
    f32x4 acc[2][4];
#pragma unroll
    for (int m = 0; m < 2; ++m)
#pragma unroll
      for (int n = 0; n < 4; ++n) acc[m][n] = (f32x4){0.f, 0.f, 0.f, 0.f};
    for (int k0 = 0; k0 < HD; k0 += 32) {
      __syncthreads();
#pragma unroll
      for (int h2 = 0; h2 < 2; ++h2) {
        int id = tid + h2 * 256;
        int br = id >> 2, bseg = id & 3;
        int bs = (bseg ^ (br & 3)) * 8;
        size_t off = (size_t)(hc * 128 + br) * HD + k0 + bseg * 8;
        *(bf16x8*)&BshH[br * 32 + bs] = *(const bf16x8*)(Bhi + off);
        *(bf16x8*)&BshL[br * 32 + bs] = *(const bf16x8*)(Blo + off);
      }
      __syncthreads();
      bf16x8 ah[2], al[2], bh[4], bl[4];
#pragma unroll
      for (int m = 0; m < 2; ++m) {
        int row = wr * 32 + m * 16 + (lane & 15);
        int sg = (k0 >> 3) + kseg;
        int sp = (sg ^ (row & 15)) * 8;
        ah[m] = *(bf16x8*)&AshH[row * 128 + sp];
        al[m] = *(bf16x8*)&AshL[row * 128 + sp];
      }
#pragma unroll
      for (int n = 0; n < 4; ++n) {
        int col = wc * 64 + n * 16 + (lane & 15);
        int s = (kseg ^ (col & 3)) * 8;
        bh[n] = *(bf16x8*)&BshH[col * 32 + s];
        bl[n] = *(bf16x8*)&BshL[col * 32 + s];
      }
#pragma unroll
      for (int m = 0; m < 2; ++m)
#pragma unroll
        for (int n = 0; n < 4; ++n) {
          acc[m][n] = __builtin_amdgcn_mfma_f32_16x16x32_bf16(ah[m], bh[n], acc[m][n], 0, 0, 0);
          acc[m][n] = __builtin_amdgcn_mfma_f32_16x16x32_bf16(al[m], bh[n], acc[m][n], 0, 0, 0);
          acc[m][n] = __builtin_amdgcn_mfma_f32_16x16x32_bf16(ah[m], bl[n], acc[m][n], 0, 0, 0);
        }
    }
#pragma unroll
    for (int n = 0; n < 4; ++n) {
      int col = hc * 128 + wc * 64 + n * 16 + (lane & 15);
      float bcol = bias[col];
      float w20 = W2[2 * col], w21 = W2[2 * col + 1];
#pragma unroll
      for (int m = 0; m < 2; ++m)
#pragma unroll
        for (int q = 0; q < 4; ++q) {
          float v = fmaxf(acc[m][n][q] + bcol, 0.f);
          ps0[m][q] += v * w20;
          ps1[m][q] += v * w21;
        }
    }
  }
#pragma unroll
  for (int m = 0; m < 2; ++m)
#pragma unroll
    for (int q = 0; q < 4; ++q) {
      float a = ps0[m][q], b = ps1[m][q];
      for (int msk = 8; msk > 0; msk >>= 1) {
        a += __shfl_xor(a, msk, 64);
        b += __shfl_xor(b, msk, 64);
      }
      if ((lane & 15) == 0) {
        int r = wr * 32 + m * 16 + (lane >> 4) * 4 + q;
        atomicAdd(&osum[r][0], a);
        atomicAdd(&osum[r][1], b);
      }
    }
  __syncthreads();
  if (tid < 64) {
    int row = n0 + tid;
    if (row < M) {
      out[(size_t)row * 2 + 0] = osum[tid][0] + b2[0];
      out[(size_t)row * 2 + 1] = osum[tid][1] + b2[1];
    }
  }
}

// Batched gather-aggregate (blockIdx.y = t): featA4[t] + scores1_4[t]; t==3 also bf16.
__global__ void k_aggB(const float* __restrict__ h4, const int* __restrict__ rowptr4,
                       const int* __restrict__ srcs4, const float* __restrict__ din4,
                       float* __restrict__ featA4, const float* __restrict__ scorer,
                       const float* __restrict__ ctlf, float* __restrict__ scores1_4,
                       unsigned short* __restrict__ outHi, unsigned short* __restrict__ outLo) {
  int t = blockIdx.y;
  int w = (blockIdx.x * blockDim.x + threadIdx.x) >> 6;
  int lane = threadIdx.x & 63;
  if (w >= NN) return;
  const float* h = h4 + (size_t)t * NN * HD;
  const int* rowptr = rowptr4 + (size_t)t * (NN + 1);
  const int* srcs = srcs4 + (size_t)t * NE;
  int beg = rowptr[w], end = rowptr[w + 1];
  float ax = 0.f, ay = 0.f;
  int e = beg;
  int l2o = lane * 2;
  for (; e + 8 <= end; e += 8) {
    int s0 = srcs[e + 0], s1 = srcs[e + 1], s2 = srcs[e + 2], s3 = srcs[e + 3];
    int s4 = srcs[e + 4], s5 = srcs[e + 5], s6 = srcs[e + 6], s7 = srcs[e + 7];
    float2 v0 = *(const float2*)&h[(size_t)s0 * HD + l2o];
    float2 v1 = *(const float2*)&h[(size_t)s1 * HD + l2o];
    float2 v2 = *(const float2*)&h[(size_t)s2 * HD + l2o];
    float2 v3 = *(const float2*)&h[(size_t)s3 * HD + l2o];
    float2 v4 = *(const float2*)&h[(size_t)s4 * HD + l2o];
    float2 v5 = *(const float2*)&h[(size_t)s5 * HD + l2o];
    float2 v6 = *(const float2*)&h[(size_t)s6 * HD + l2o];
    float2 v7 = *(const float2*)&h[(size_t)s7 * HD + l2o];
    ax += ((v0.x + v1.x) + (v2.x + v3.x)) + ((v4.x + v5.x) + (v6.x + v7.x));
    ay += ((v0.y + v1.y) + (v2.y + v3.y)) + ((v4.y + v5.y) + (v6.y + v7.y));
  }
  for (; e + 2 <= end; e += 2) {
    int s0 = srcs[e + 0], s1 = srcs[e + 1];
    float2 v0 = *(const float2*)&h[(size_t)s0 * HD + l2o];
    float2 v1 = *(const float2*)&h[(size_t)s1 * HD + l2o];
    ax += v0.x + v1.x;
    ay += v0.y + v1.y;
  }
  for (; e < end; ++e) {
    int s = srcs[e];
    float2 v = *(const float2*)&h[(size_t)s * HD + l2o];
    ax += v.x; ay += v.y;
  }
  float dn = din4[(size_t)t * NN + w];
  ax *= dn; ay *= dn;
  ax = ax >= 0.f ? ax : RSLOPE * ax;
  ay = ay >= 0.f ? ay : RSLOPE * ay;
  *(float2*)&featA4[((size_t)t * NN + w) * HD + l2o] = make_float2(ax, ay);
  if (t == NT - 1) {
    unsigned short hx = f2bf(ax), hy = f2bf(ay);
    unsigned short lx = f2bf(ax - bf2f(hx)), ly = f2bf(ay - bf2f(hy));
    *(ushort2*)&outHi[(size_t)w * HD + l2o] = make_ushort2(hx, hy);
    *(ushort2*)&outLo[(size_t)w * HD + l2o] = make_ushort2(lx, ly);
  }
  float sp = ax * scorer[l2o] + ay * scorer[l2o + 1];
  sp = wsumf(sp);
  if (lane == 0) scores1_4[(size_t)t * NN + w] = sp / ctlf[C_NORM1];
}

extern "C" void kernel_launch(void* const* d_in, const int* in_sizes, int n_in,
                              void* d_out, int out_size, void* d_ws, size_t ws_size,
                              hipStream_t stream) {
  (void)in_sizes; (void)n_in; (void)out_size; (void)ws_size;
  const float* feats = (const float*)d_in[0];
  const int* edges = (const int*)d_in[1];
  const float* scorer0 = (const float*)d_in[2];
  const float* scorer1 = (const float*)d_in[3];
  const float* gcnW0 = (const float*)d_in[4];
  const float* gcnW1 = (const float*)d_in[5];
  const float* g0[9];
  const float* g1[9];
  for (int i = 0; i < 9; ++i) {
    g0[i] = (const float*)d_in[6 + i];
    g1[i] = (const float*)d_in[15 + i];
  }
  const float* mlpW1 = (const float*)d_in[24];
  const float* mlpB1 = (const float*)d_in[25];
  const float* mlpW2 = (const float*)d_in[26];
  const float* mlpB2 = (const float*)d_in[27];
  float* out = (float*)d_out;

  char* p = (char*)d_ws;
  auto carve = [&p](size_t bytes) {
    void* r = (void*)p;
    p += (bytes + 511) & ~(size_t)511;
    return r;
  };
  float* featA4 = (float*)carve((size_t)NT * NN * HD * 4);   // 102.4 MB
  float* hbuf4  = (float*)carve((size_t)NT * NN * HD * 4);   // 102.4 MB
  unsigned short* fahi = (unsigned short*)carve((size_t)NN * HD * 2);
  unsigned short* falo = (unsigned short*)carve((size_t)NN * HD * 2);
  int* srcs4   = (int*)carve((size_t)NT * NE * 4);
  int* rowptr4 = (int*)carve((size_t)NT * (NN + 1) * 4);
  unsigned int* chist = (unsigned int*)carve((size_t)2 * NT * NCH * WPC * 4);
  unsigned int* lbase = (unsigned int*)carve((size_t)NT * NCH * NN * 4);
  int* bsum4   = (int*)carve((size_t)NT * SCAN_BLOCKS * 4);
  float* dor4  = (float*)carve((size_t)NT * NN * 4);
  float* din4  = (float*)carve((size_t)NT * NN * 4);
  float* scores0 = (float*)carve((size_t)NT * NN * 4);
  float* scores1_4 = (float*)carve((size_t)NT * NN * 4);
  float* ctlf  = (float*)carve(64 * 4);
  unsigned short* bt0hi = (unsigned short*)carve((size_t)NT * BT0SZ * 2);
  unsigned short* bt0lo = (unsigned short*)carve((size_t)NT * BT0SZ * 2);
  unsigned short* bt1hi = (unsigned short*)carve((size_t)NT * BT1SZ * 2);
  unsigned short* bt1lo = (unsigned short*)carve((size_t)NT * BT1SZ * 2);
  unsigned short* rqThi = (unsigned short*)carve((size_t)HD * FD * 2);
  unsigned short* rqTlo = (unsigned short*)carve((size_t)HD * FD * 2);
  float* ubuf_f = (float*)carve((size_t)FD * HD * 4);
  float* hzbuf  = (float*)carve((size_t)FD * HD * 4);
  unsigned short* acat0hi = (unsigned short*)carve((size_t)3 * FD * 2 * FD * 2);
  unsigned short* acat0lo = (unsigned short*)carve((size_t)3 * FD * 2 * FD * 2);
  unsigned short* acat1hi = (unsigned short*)carve((size_t)3 * HD * 2 * HD * 2);
  unsigned short* acat1lo = (unsigned short*)carve((size_t)3 * HD * 2 * HD * 2);
  unsigned short* uh0hi = (unsigned short*)carve((size_t)FD * FD * 2);
  unsigned short* uh0lo = (unsigned short*)carve((size_t)FD * FD * 2);
  unsigned short* uh1hi = (unsigned short*)carve((size_t)HD * HD * 2);
  unsigned short* uh1lo = (unsigned short*)carve((size_t)HD * HD * 2);
  float* Q0 = (float*)carve((size_t)FD * HD * 4);
  float* Q1 = (float*)carve((size_t)HD * HD * 4);
  unsigned short* mW1thi = (unsigned short*)carve((size_t)CH * HD * 2);
  unsigned short* mW1tlo = (unsigned short*)carve((size_t)CH * HD * 2);
  unsigned int* barbuf = (unsigned int*)carve(64 * 4);

  // ---- all startup work in one dispatch (norms, transposes, splits, Q copies,
  //      barrier-counter zeroing) ----
  k_startup<<<SU_TOTAL, 256, 0, stream>>>(
      scorer0, scorer1, ctlf, mlpW1, mW1thi, mW1tlo, gcnW0, gcnW1,
      bt0hi, bt0lo, bt1hi, bt1lo,
      g0[0], g0[1], g0[3], g0[4], g0[6], acat0hi, acat0lo,
      g1[0], g1[1], g1[3], g1[4], g1[6], acat1hi, acat1lo,
      g0[7], uh0hi, uh0lo, g1[7], uh1hi, uh1lo, Q0, Q1, barbuf);

  // batched preprocessing
  k_scores0_all<<<dim3(12500, NT), 256, 0, stream>>>(feats, scorer0, ctlf, scores0);
  k_degC<<<dim3(NCH, NT), 1024, 0, stream>>>(edges, chist);
  k_scanB<<<dim3(SCAN_BLOCKS, NT), 1024, 0, stream>>>(chist, lbase, dor4, din4, rowptr4, bsum4);
  k_scan2b<<<NT, 1024, 0, stream>>>(rowptr4, bsum4);
  k_scatC<<<dim3(NCH, NT), 1024, 0, stream>>>(edges, rowptr4, lbase, srcs4);
  // all 4 layer-0 pools: z^T into bt0[t] cols [0,FD)
  k_pool<8><<<NT, 1024, 0, stream>>>(feats, (long)NN * FD, scores0, NN,
                                     bt0hi, bt0lo, (long)BT0SZ, 2 * FD);

  // ---- full L0 GRU chain in ONE persistent kernel (was 8 launches) ----
  k_gruChain<<<3 * FD / 64, 256, 0, stream>>>(
      acat0hi, acat0lo, bt0hi, bt0lo, (long)BT0SZ, FD,
      g0[2], g0[5], g0[8], Q0, ubuf_f, hzbuf, rqThi, rqTlo,
      uh0hi, uh0lo, barbuf + 0);

  const int gM = (NN + 63) / 64;

  // ---- all 4 layer-0 convs, one launch ----
  k_convL0<<<dim3(gM, 1, NT), 256, 0, stream>>>(feats, bt0hi, bt0lo, hbuf4, dor4);

  // ---- all 4 aggregates, one launch (also layer-1 scores; t=3 bf16 out) ----
  k_aggB<<<dim3(12500, NT), 256, 0, stream>>>(hbuf4, rowptr4, srcs4, din4, featA4,
                                              scorer1, ctlf, scores1_4, fahi, falo);

  // ---- all 4 layer-1 pools, one launch: z^T into bt1[t] ----
  k_pool<7><<<NT, 1024, 0, stream>>>(featA4, (long)NN * HD, scores1_4, NN,
                                     bt1hi, bt1lo, (long)BT1SZ, 2 * HD);

  // ---- L1 GRU chain in ONE persistent kernel ----
  k_gruChain<<<3 * HD / 64, 256, 0, stream>>>(
      acat1hi, acat1lo, bt1hi, bt1lo, (long)BT1SZ, HD,
      g1[2], g1[5], g1[8], Q1, ubuf_f, hzbuf, rqThi, rqTlo,
      uh1hi, uh1lo, barbuf + 1);

  // ---- final layer-1 conv (t=3; W slot = (3+1)&3 = 0), then fused agg+MLP ----
  k_gemm3<<<dim3(gM, 1), 256, 0, stream>>>(fahi, falo, HD,
                                           bt1hi + HD, bt1lo + HD, 2 * HD,
                                           hbuf4, HD, NN, HD, dor4 + (size_t)3 * NN);
  k_gemmMLPagg<<<gM, 256, 0, stream>>>(hbuf4, rowptr4 + (size_t)3 * (NN + 1),
                                       srcs4 + (size_t)3 * NE, din4 + (size_t)3 * NN,
                                       mW1thi, mW1tlo, mlpB1, mlpW2, mlpB2, out, NN);
}